// Round 6
// baseline (3690.953 us; speedup 1.0000x reference)
//
#include <hip/hip_runtime.h>

#define T_TOK 8192   // B*S tokens
#define DIM   768
#define NCB   8192   // codebook entries
#define KSEL  8
#define BT    32     // tokens per workgroup
#define BN    128    // codes per tile
#define BD    32     // D-chunk staged in LDS

// ---------------------------------------------------------------------------
// Kernel A: ||row||^2 — bit-exact modern-numpy pairwise_sum (npyv/AVX-512
// W=16) over t[k]=fl32(v*v). 768 -> 384/192/96 recursion; 96-base: 4 16-lane
// vector accs, vector remainder into r0, (r0+r1)+(r2+r3), then the
// _mm512_reduce_add_ps tree. [frozen: R5 green — do not change rounding]
// ---------------------------------------------------------------------------
__global__ __launch_bounds__(256) void sq_pairwise_kernel(
    const float* __restrict__ cb, const float* __restrict__ x,
    float* __restrict__ c2out, float* __restrict__ x2out)
{
  #pragma clang fp contract(off)
  __shared__ float part[32][8];
  const int tid = threadIdx.x;
  const int row = blockIdx.x * 32 + (tid >> 3);       // 0..16383
  const int b   = tid & 7;                            // 96-block index
  const float* src = (row < NCB) ? (cb + (size_t)row * DIM)
                                 : (x + (size_t)(row - NCB) * DIM);
  const float* a = src + 96 * b;

  float s[16];
  #pragma unroll
  for (int l = 0; l < 16; ++l) {
    float v, t;
    v = a[l];       t = v * v; float r0 = t;
    v = a[64 + l];  t = v * v; r0 = r0 + t;
    v = a[80 + l];  t = v * v; r0 = r0 + t;
    v = a[16 + l];  t = v * v; float r1 = t;
    v = a[32 + l];  t = v * v; float r2 = t;
    v = a[48 + l];  t = v * v; float r3 = t;
    s[l] = (r0 + r1) + (r2 + r3);
  }
  float t1[8], t2[4];
  #pragma unroll
  for (int i = 0; i < 8; ++i) t1[i] = s[i] + s[i + 8];
  #pragma unroll
  for (int j = 0; j < 4; ++j) t2[j] = t1[j] + t1[j + 4];
  part[tid >> 3][b] = (t2[0] + t2[2]) + (t2[1] + t2[3]);
  __syncthreads();

  if (b == 0) {
    const float* p = part[tid >> 3];
    float res = ((p[0] + p[1]) + (p[2] + p[3])) + ((p[4] + p[5]) + (p[6] + p[7]));
    if (row < NCB) c2out[row] = res;
    else           x2out[row - NCB] = res;
  }
}

// ---------------------------------------------------------------------------
// Kernel B: split-K distance + per-split exact top-8 candidates.
// blockIdx.x = token block (256), blockIdx.y = code split. Arithmetic is the
// frozen R5 pipeline: unfused SSE1 4-lane comb (lane = k&3, ascending k),
// reduce (l0+l2)+(l1+l3), neg = fl(fl(2*xc-x2)-c2), key = -neg (exact).
// Split lists merge exactly later (disjoint id ranges, exact fp32 keys).
// ---------------------------------------------------------------------------
__global__ __launch_bounds__(256) void dist_topk_kernel(
    const float* __restrict__ x, const float* __restrict__ cb,
    const float* __restrict__ c2g, const float* __restrict__ x2g,
    float* __restrict__ ws, int ncodes)
{
  #pragma clang fp contract(off)
  __shared__ float smem[9600];                               // 38.4 KB
  float (*xs)[36]       = (float(*)[36])smem;                // [BD][36]
  float (*cs)[BN + 4]   = (float(*)[BN + 4])(smem + 1152);   // [BD][132]
  float (*dist)[BN + 4] = (float(*)[BN + 4])(smem + 5376);   // [BT][132]

  const int tid  = threadIdx.x;
  const int t0   = blockIdx.x * BT;
  const int spl  = blockIdx.y;
  const int nbeg = spl * ncodes;

  const int gx = tid & 31;   // 4-code group
  const int gy = tid >> 5;   // 4-token group

  const int tt = tid >> 3;   // top-k: token 0..31
  const int cc = tid & 7;    // top-k: scan lane 0..7

  const int xr   = tid >> 3;         // x stager: row 0..31
  const int xc4  = (tid & 7) * 4;    // x stager: d offset
  const int crow = tid >> 1;         // c stager: row 0..127
  const int cseg = (tid & 1) * 16;   // c stager: d offset

  float x2r[4];
  #pragma unroll
  for (int i = 0; i < 4; ++i) x2r[i] = x2g[t0 + gy * 4 + i];

  float bdist[KSEL]; int bid[KSEL];
  #pragma unroll
  for (int i = 0; i < KSEL; ++i) { bdist[i] = __builtin_inff(); bid[i] = 0x7fffffff; }
  float bmax = __builtin_inff(); int bmaxid = 0x7fffffff; int bslot = 0;

  for (int n0 = nbeg; n0 < nbeg + ncodes; n0 += BN) {
    float c2r[4];
    #pragma unroll
    for (int j = 0; j < 4; ++j) c2r[j] = c2g[n0 + gx * 4 + j];

    // acc[token][code][sse_lane]; lane = k & 3
    float acc[4][4][4];
    #pragma unroll
    for (int i = 0; i < 4; ++i)
      #pragma unroll
      for (int j = 0; j < 4; ++j)
        #pragma unroll
        for (int l = 0; l < 4; ++l) acc[i][j][l] = 0.f;

    float4 xv, cva, cvb, cvc, cvd;
    {
      xv = *(const float4*)(x + (size_t)(t0 + xr) * DIM + xc4);
      const float* cp = cb + (size_t)(n0 + crow) * DIM + cseg;
      cva = *(const float4*)(cp + 0);
      cvb = *(const float4*)(cp + 4);
      cvc = *(const float4*)(cp + 8);
      cvd = *(const float4*)(cp + 12);
    }

    for (int d0 = 0; d0 < DIM; d0 += BD) {
      __syncthreads();
      xs[xc4 + 0][xr] = xv.x;
      xs[xc4 + 1][xr] = xv.y;
      xs[xc4 + 2][xr] = xv.z;
      xs[xc4 + 3][xr] = xv.w;
      cs[cseg +  0][crow] = cva.x;  cs[cseg +  1][crow] = cva.y;
      cs[cseg +  2][crow] = cva.z;  cs[cseg +  3][crow] = cva.w;
      cs[cseg +  4][crow] = cvb.x;  cs[cseg +  5][crow] = cvb.y;
      cs[cseg +  6][crow] = cvb.z;  cs[cseg +  7][crow] = cvb.w;
      cs[cseg +  8][crow] = cvc.x;  cs[cseg +  9][crow] = cvc.y;
      cs[cseg + 10][crow] = cvc.z;  cs[cseg + 11][crow] = cvc.w;
      cs[cseg + 12][crow] = cvd.x;  cs[cseg + 13][crow] = cvd.y;
      cs[cseg + 14][crow] = cvd.z;  cs[cseg + 15][crow] = cvd.w;
      __syncthreads();

      const int dn = d0 + BD;
      if (dn < DIM) {
        xv = *(const float4*)(x + (size_t)(t0 + xr) * DIM + dn + xc4);
        const float* cp = cb + (size_t)(n0 + crow) * DIM + dn + cseg;
        cva = *(const float4*)(cp + 0);
        cvb = *(const float4*)(cp + 4);
        cvc = *(const float4*)(cp + 8);
        cvd = *(const float4*)(cp + 12);
      }

      // SSE1 einsum comb: lane (k&3) += fl(x*c), ascending k, no FMA.
      #pragma unroll
      for (int k = 0; k < BD; ++k) {
        const int ln = k & 3;
        const float4 xa = *(const float4*)(&xs[k][gy * 4]);
        const float4 cv = *(const float4*)(&cs[k][gx * 4]);
        acc[0][0][ln] = acc[0][0][ln] + xa.x * cv.x;
        acc[0][1][ln] = acc[0][1][ln] + xa.x * cv.y;
        acc[0][2][ln] = acc[0][2][ln] + xa.x * cv.z;
        acc[0][3][ln] = acc[0][3][ln] + xa.x * cv.w;
        acc[1][0][ln] = acc[1][0][ln] + xa.y * cv.x;
        acc[1][1][ln] = acc[1][1][ln] + xa.y * cv.y;
        acc[1][2][ln] = acc[1][2][ln] + xa.y * cv.z;
        acc[1][3][ln] = acc[1][3][ln] + xa.y * cv.w;
        acc[2][0][ln] = acc[2][0][ln] + xa.z * cv.x;
        acc[2][1][ln] = acc[2][1][ln] + xa.z * cv.y;
        acc[2][2][ln] = acc[2][2][ln] + xa.z * cv.z;
        acc[2][3][ln] = acc[2][3][ln] + xa.z * cv.w;
        acc[3][0][ln] = acc[3][0][ln] + xa.w * cv.x;
        acc[3][1][ln] = acc[3][1][ln] + xa.w * cv.y;
        acc[3][2][ln] = acc[3][2][ln] + xa.w * cv.z;
        acc[3][3][ln] = acc[3][3][ln] + xa.w * cv.w;
      }
    }

    #pragma unroll
    for (int i = 0; i < 4; ++i) {
      float4 dv;
      {
        float xc0 = (acc[i][0][0] + acc[i][0][2]) + (acc[i][0][1] + acc[i][0][3]);
        float xc1 = (acc[i][1][0] + acc[i][1][2]) + (acc[i][1][1] + acc[i][1][3]);
        float xc2 = (acc[i][2][0] + acc[i][2][2]) + (acc[i][2][1] + acc[i][2][3]);
        float xc3 = (acc[i][3][0] + acc[i][3][2]) + (acc[i][3][1] + acc[i][3][3]);
        float s0 = 2.0f * xc0 - x2r[i]; dv.x = -(s0 - c2r[0]);
        float s1 = 2.0f * xc1 - x2r[i]; dv.y = -(s1 - c2r[1]);
        float s2 = 2.0f * xc2 - x2r[i]; dv.z = -(s2 - c2r[2]);
        float s3 = 2.0f * xc3 - x2r[i]; dv.w = -(s3 - c2r[3]);
      }
      *(float4*)(&dist[gy * 4 + i][gx * 4]) = dv;
    }
    __syncthreads();

    // per-lane top-8 (ids ascend in scan; strict < = stable lower-id on ties)
    #pragma unroll
    for (int i = 0; i < BN / 8; ++i) {
      const float dval = dist[tt][cc + 8 * i];
      const int   id   = n0 + cc + 8 * i;
      if (dval < bmax) {
        #pragma unroll
        for (int q = 0; q < KSEL; ++q)
          if (q == bslot) { bdist[q] = dval; bid[q] = id; }
        bmax = bdist[0]; bmaxid = bid[0]; bslot = 0;
        #pragma unroll
        for (int q = 1; q < KSEL; ++q)
          if (bdist[q] > bmax || (bdist[q] == bmax && bid[q] > bmaxid)) {
            bmax = bdist[q]; bmaxid = bid[q]; bslot = q;
          }
      }
    }
  }

  // ---- merge 8 lanes x 8 -> this split's top-8; write (val,id) to ws ----
  __syncthreads();
  float* md = smem;
  int*   mi = (int*)(smem + 2048);
  #pragma unroll
  for (int j = 0; j < KSEL; ++j) {
    md[tt * 64 + cc * KSEL + j] = bdist[j];
    mi[tt * 64 + cc * KSEL + j] = bid[j];
  }
  __syncthreads();
  if (tid < BT) {
    float* mdt = md + tid * 64;
    int*   mit = mi + tid * 64;
    const size_t base = ((size_t)spl * T_TOK + (t0 + tid)) * 16;
    for (int r = 0; r < KSEL; ++r) {
      float best = __builtin_inff(); int bestid = 0x7fffffff; int bs = 0;
      for (int s = 0; s < 64; ++s) {
        const float dv = mdt[s]; const int iv = mit[s];
        if (dv < best || (dv == best && iv < bestid)) { best = dv; bestid = iv; bs = s; }
      }
      mdt[bs] = __builtin_inff();
      ws[base + r] = best;
      ((int*)ws)[base + 8 + r] = bestid;
    }
  }
}

// ---------------------------------------------------------------------------
// Kernel C: exact (val,id)-lex merge of nsplit*8 candidates -> final ids,
// fused with the gather-mean of the 8 selected rows.
// ---------------------------------------------------------------------------
__global__ __launch_bounds__(192) void merge_gather_kernel(
    const float* __restrict__ cb, const float* __restrict__ ws,
    float* __restrict__ out, float* __restrict__ out_ids, int nsplit)
{
  __shared__ float mv[64];
  __shared__ int   mid[64];
  __shared__ int   ssel[KSEL];

  const int t   = blockIdx.x;
  const int tid = threadIdx.x;
  const int ncand = nsplit * KSEL;

  if (tid < ncand) {
    const int s = tid >> 3, r = tid & 7;
    const size_t base = ((size_t)s * T_TOK + t) * 16;
    mv[tid]  = ws[base + r];
    mid[tid] = ((const int*)ws)[base + 8 + r];
  }
  __syncthreads();

  if (tid == 0) {
    for (int r = 0; r < KSEL; ++r) {
      float best = __builtin_inff(); int bestid = 0x7fffffff; int bs = 0;
      for (int s = 0; s < ncand; ++s) {
        const float dv = mv[s]; const int iv = mid[s];
        if (dv < best || (dv == best && iv < bestid)) { best = dv; bestid = iv; bs = s; }
      }
      mv[bs] = __builtin_inff();
      ssel[r] = bestid;
      out_ids[(size_t)t * KSEL + r] = (float)bestid;
    }
  }
  __syncthreads();

  float4 s4 = make_float4(0.f, 0.f, 0.f, 0.f);
  #pragma unroll
  for (int r = 0; r < KSEL; ++r) {
    const float4 v = *(const float4*)(cb + (size_t)ssel[r] * DIM + tid * 4);
    s4.x += v.x; s4.y += v.y; s4.z += v.z; s4.w += v.w;
  }
  s4.x *= 0.125f; s4.y *= 0.125f; s4.z *= 0.125f; s4.w *= 0.125f;
  *(float4*)(out + (size_t)t * DIM + tid * 4) = s4;
}

extern "C" void kernel_launch(void* const* d_in, const int* in_sizes, int n_in,
                              void* d_out, int out_size, void* d_ws, size_t ws_size,
                              hipStream_t stream) {
  (void)in_sizes; (void)n_in; (void)out_size;
  const float* x   = (const float*)d_in[0];
  const float* cbk = (const float*)d_in[1];
  float* out     = (float*)d_out;
  float* c2buf   = out;                   // out[0:8192], overwritten later
  float* x2buf   = out + NCB;             // out[8192:16384], overwritten later
  float* out_ids = out + (size_t)T_TOK * DIM;
  float* ws      = (float*)d_ws;

  // pick the largest split count whose candidate buffer fits the workspace
  int nsplit = 1;
  for (int s = 8; s >= 1; s >>= 1) {
    if ((size_t)s * T_TOK * 16 * 4 <= ws_size) { nsplit = s; break; }
  }
  const int ncodes = NCB / nsplit;

  sq_pairwise_kernel<<<(NCB + T_TOK) / 32, 256, 0, stream>>>(cbk, x, c2buf, x2buf);
  dist_topk_kernel<<<dim3(T_TOK / BT, nsplit), 256, 0, stream>>>(
      x, cbk, c2buf, x2buf, ws, ncodes);
  merge_gather_kernel<<<T_TOK, 192, 0, stream>>>(cbk, ws, out, out_ids, nsplit);
}

// Round 7
// 2399.261 us; speedup vs baseline: 1.5384x; 1.5384x over previous
//
#include <hip/hip_runtime.h>

#define T_TOK 8192   // B*S tokens
#define DIM   768
#define NCB   8192   // codebook entries
#define KSEL  8
#define BT    64     // tokens per workgroup
#define BN    128    // codes per tile
#define BD    32     // d-chunk staged in LDS
#define NQ    (BD/4) // 8 k-quads per chunk
#define CSTR  9      // cs quad-row: 16 groups of (8 codes + 1 pad) float4
#define DSTR  140    // dist row stride in floats (16B-aligned, 2-way banks)

typedef float v2f __attribute__((ext_vector_type(2)));

// ---------------------------------------------------------------------------
// Kernel A: ||row||^2 — bit-exact modern-numpy pairwise_sum (npyv/AVX-512
// W=16) over t[k]=fl32(v*v). [frozen: R5 green — do not change rounding]
// ---------------------------------------------------------------------------
__global__ __launch_bounds__(256) void sq_pairwise_kernel(
    const float* __restrict__ cb, const float* __restrict__ x,
    float* __restrict__ c2out, float* __restrict__ x2out)
{
  #pragma clang fp contract(off)
  __shared__ float part[32][8];
  const int tid = threadIdx.x;
  const int row = blockIdx.x * 32 + (tid >> 3);       // 0..16383
  const int b   = tid & 7;                            // 96-block index
  const float* src = (row < NCB) ? (cb + (size_t)row * DIM)
                                 : (x + (size_t)(row - NCB) * DIM);
  const float* a = src + 96 * b;

  float s[16];
  #pragma unroll
  for (int l = 0; l < 16; ++l) {
    float v, t;
    v = a[l];       t = v * v; float r0 = t;
    v = a[64 + l];  t = v * v; r0 = r0 + t;
    v = a[80 + l];  t = v * v; r0 = r0 + t;
    v = a[16 + l];  t = v * v; float r1 = t;
    v = a[32 + l];  t = v * v; float r2 = t;
    v = a[48 + l];  t = v * v; float r3 = t;
    s[l] = (r0 + r1) + (r2 + r3);
  }
  float t1[8], t2[4];
  #pragma unroll
  for (int i = 0; i < 8; ++i) t1[i] = s[i] + s[i + 8];
  #pragma unroll
  for (int j = 0; j < 4; ++j) t2[j] = t1[j] + t1[j + 4];
  part[tid >> 3][b] = (t2[0] + t2[2]) + (t2[1] + t2[3]);
  __syncthreads();

  if (b == 0) {
    const float* p = part[tid >> 3];
    float res = ((p[0] + p[1]) + (p[2] + p[3])) + ((p[4] + p[5]) + (p[6] + p[7]));
    if (row < NCB) c2out[row] = res;
    else           x2out[row - NCB] = res;
  }
}

// ---------------------------------------------------------------------------
// Kernel B: split-K distance + per-split exact top-8.
// Frozen arithmetic (R5): unfused SSE1 4-lane comb (lane = k&3, ascending k),
// reduce (l0+l2)+(l1+l3), neg = fl(fl(2*xc-x2)-c2), key = -neg (exact).
// New: quad-interleaved LDS ([d/4][row] float4, contiguous b128 staging),
// 4 tok x 8 codes per thread (1.5 B/MAC), float2-packed unfused MAC
// (v_pk_mul/v_pk_add are bit-identical independent IEEE fp32 ops).
// ---------------------------------------------------------------------------
__global__ __launch_bounds__(256, 2) void dist_topk_kernel(
    const float* __restrict__ x, const float* __restrict__ cb,
    const float* __restrict__ c2g, const float* __restrict__ x2g,
    float* __restrict__ ws, int ncodes)
{
  #pragma clang fp contract(off)
  __shared__ float4 smem4[2240];                 // 35840 B
  float*  smem = (float*)smem4;
  float4* xs4  = smem4;                          // [NQ][BT]       = 512 f4
  float4* cs4  = smem4 + NQ * BT;                // [NQ][16*CSTR]  = 1152 f4
  // dist overlays everything: [BT][DSTR] floats = 2240 f4

  const int tid  = threadIdx.x;
  const int t0   = blockIdx.x * BT;
  const int nbeg = blockIdx.y * ncodes;

  const int gx = tid & 15;        // 8-code group
  const int gy = tid >> 4;        // 4-token group

  const int tt = tid >> 2;        // scan: token 0..63
  const int cc = tid & 3;         // scan: lane 0..3

  const int xr  = tid >> 2;       // x stager: token 0..63, quads xq & xq+4
  const int xq  = tid & 3;
  const int cr  = tid >> 1;       // c stager: code 0..127, quads cq0..cq0+3
  const int cq0 = (tid & 1) * 4;
  const int crg = (cr >> 3) * CSTR + (cr & 7);   // padded cs column

  float x2r[4];
  #pragma unroll
  for (int i = 0; i < 4; ++i) x2r[i] = x2g[t0 + gy * 4 + i];

  float bdist[KSEL]; int bid[KSEL];
  #pragma unroll
  for (int i = 0; i < KSEL; ++i) { bdist[i] = __builtin_inff(); bid[i] = 0x7fffffff; }
  float bmax = __builtin_inff(); int bmaxid = 0x7fffffff; int bslot = 0;

  for (int n0 = nbeg; n0 < nbeg + ncodes; n0 += BN) {
    float c2r[8];
    #pragma unroll
    for (int j = 0; j < 8; ++j) c2r[j] = c2g[n0 + gx * 8 + j];

    v2f accL[4][8], accH[4][8];    // SSE lanes (0,1) and (2,3)
    #pragma unroll
    for (int i = 0; i < 4; ++i)
      #pragma unroll
      for (int j = 0; j < 8; ++j) { accL[i][j] = (v2f)0.f; accH[i][j] = (v2f)0.f; }

    float4 xpre0, xpre1, cpre0, cpre1, cpre2, cpre3;
    {
      const float* xp = x + (size_t)(t0 + xr) * DIM + xq * 4;
      xpre0 = *(const float4*)xp;
      xpre1 = *(const float4*)(xp + 16);
      const float* cp = cb + (size_t)(n0 + cr) * DIM + cq0 * 4;
      cpre0 = *(const float4*)(cp + 0);
      cpre1 = *(const float4*)(cp + 4);
      cpre2 = *(const float4*)(cp + 8);
      cpre3 = *(const float4*)(cp + 12);
    }

    for (int d0 = 0; d0 < DIM; d0 += BD) {
      __syncthreads();                 // prev chunk reads / prev tile dist done
      xs4[xq * BT + xr]       = xpre0;
      xs4[(xq + 4) * BT + xr] = xpre1;
      cs4[(cq0 + 0) * 16 * CSTR + crg] = cpre0;
      cs4[(cq0 + 1) * 16 * CSTR + crg] = cpre1;
      cs4[(cq0 + 2) * 16 * CSTR + crg] = cpre2;
      cs4[(cq0 + 3) * 16 * CSTR + crg] = cpre3;
      __syncthreads();

      const int dn = d0 + BD;
      if (dn < DIM) {
        const float* xp = x + (size_t)(t0 + xr) * DIM + dn + xq * 4;
        xpre0 = *(const float4*)xp;
        xpre1 = *(const float4*)(xp + 16);
        const float* cp = cb + (size_t)(n0 + cr) * DIM + dn + cq0 * 4;
        cpre0 = *(const float4*)(cp + 0);
        cpre1 = *(const float4*)(cp + 4);
        cpre2 = *(const float4*)(cp + 8);
        cpre3 = *(const float4*)(cp + 12);
      }

      #pragma unroll
      for (int q = 0; q < NQ; ++q) {
        float4 xa[4];
        #pragma unroll
        for (int i = 0; i < 4; ++i) xa[i] = xs4[q * BT + gy * 4 + i];
        #pragma unroll
        for (int j = 0; j < 8; ++j) {
          const float4 cv = cs4[q * 16 * CSTR + gx * CSTR + j];
          #pragma unroll
          for (int i = 0; i < 4; ++i) {
            v2f a, b, p;
            a[0] = xa[i].x; a[1] = xa[i].y;
            b[0] = cv.x;    b[1] = cv.y;
            p = a * b;                      // 2 independent fl32 muls
            accL[i][j] = accL[i][j] + p;    // 2 independent fl32 adds
            a[0] = xa[i].z; a[1] = xa[i].w;
            b[0] = cv.z;    b[1] = cv.w;
            p = a * b;
            accH[i][j] = accH[i][j] + p;
          }
        }
      }
    }

    __syncthreads();                   // MAC LDS reads done; dist may overwrite
    #pragma unroll
    for (int i = 0; i < 4; ++i) {
      float v[8];
      #pragma unroll
      for (int j = 0; j < 8; ++j) {
        // einsum reduce (l0+l2)+(l1+l3), then literal numpy combine
        float xc = (accL[i][j][0] + accH[i][j][0]) + (accL[i][j][1] + accH[i][j][1]);
        float s  = 2.0f * xc - x2r[i];
        v[j] = -(s - c2r[j]);
      }
      float4* dp = (float4*)&smem[(gy * 4 + i) * DSTR + gx * 8];
      dp[0] = make_float4(v[0], v[1], v[2], v[3]);
      dp[1] = make_float4(v[4], v[5], v[6], v[7]);
    }
    __syncthreads();

    // per-lane top-8 (ids ascend in scan; strict < = stable lower-id on ties)
    #pragma unroll
    for (int i2 = 0; i2 < BN / 4; ++i2) {
      const float dval = smem[tt * DSTR + cc + 4 * i2];
      const int   id   = n0 + cc + 4 * i2;
      if (dval < bmax) {
        #pragma unroll
        for (int q = 0; q < KSEL; ++q)
          if (q == bslot) { bdist[q] = dval; bid[q] = id; }
        bmax = bdist[0]; bmaxid = bid[0]; bslot = 0;
        #pragma unroll
        for (int q = 1; q < KSEL; ++q)
          if (bdist[q] > bmax || (bdist[q] == bmax && bid[q] > bmaxid)) {
            bmax = bdist[q]; bmaxid = bid[q]; bslot = q;
          }
      }
    }
    // next tile's staging is gated by the d-loop top barrier
  }

  // ---- merge 4 lanes x 8 -> this split's top-8 per token; write to ws ----
  __syncthreads();                     // last scan's dist reads done
  float* md = smem;                    // [64][32] floats
  int*   mi = (int*)smem + 2048;       // [64][32] ints
  #pragma unroll
  for (int j = 0; j < KSEL; ++j) {
    md[tt * 32 + cc * KSEL + j] = bdist[j];
    mi[tt * 32 + cc * KSEL + j] = bid[j];
  }
  __syncthreads();
  if (tid < BT) {
    float* mdt = md + tid * 32;
    int*   mit = mi + tid * 32;
    const size_t base = ((size_t)blockIdx.y * T_TOK + (t0 + tid)) * 16;
    for (int r = 0; r < KSEL; ++r) {
      float best = __builtin_inff(); int bestid = 0x7fffffff; int bs = 0;
      for (int s = 0; s < 32; ++s) {
        const float dv = mdt[s]; const int iv = mit[s];
        if (dv < best || (dv == best && iv < bestid)) { best = dv; bestid = iv; bs = s; }
      }
      mdt[bs] = __builtin_inff();
      ws[base + r] = best;
      ((int*)ws)[base + 8 + r] = bestid;
    }
  }
}

// ---------------------------------------------------------------------------
// Kernel C: exact (val,id)-lex merge of nsplit*8 candidates -> final ids,
// fused with the gather-mean of the 8 selected rows.
// ---------------------------------------------------------------------------
__global__ __launch_bounds__(192) void merge_gather_kernel(
    const float* __restrict__ cb, const float* __restrict__ ws,
    float* __restrict__ out, float* __restrict__ out_ids, int nsplit)
{
  __shared__ float mv[64];
  __shared__ int   mid[64];
  __shared__ int   ssel[KSEL];

  const int t   = blockIdx.x;
  const int tid = threadIdx.x;
  const int ncand = nsplit * KSEL;

  if (tid < ncand) {
    const int s = tid >> 3, r = tid & 7;
    const size_t base = ((size_t)s * T_TOK + t) * 16;
    mv[tid]  = ws[base + r];
    mid[tid] = ((const int*)ws)[base + 8 + r];
  }
  __syncthreads();

  if (tid == 0) {
    for (int r = 0; r < KSEL; ++r) {
      float best = __builtin_inff(); int bestid = 0x7fffffff; int bs = 0;
      for (int s = 0; s < ncand; ++s) {
        const float dv = mv[s]; const int iv = mid[s];
        if (dv < best || (dv == best && iv < bestid)) { best = dv; bestid = iv; bs = s; }
      }
      mv[bs] = __builtin_inff();
      ssel[r] = bestid;
      out_ids[(size_t)t * KSEL + r] = (float)bestid;
    }
  }
  __syncthreads();

  float4 s4 = make_float4(0.f, 0.f, 0.f, 0.f);
  #pragma unroll
  for (int r = 0; r < KSEL; ++r) {
    const float4 v = *(const float4*)(cb + (size_t)ssel[r] * DIM + tid * 4);
    s4.x += v.x; s4.y += v.y; s4.z += v.z; s4.w += v.w;
  }
  s4.x *= 0.125f; s4.y *= 0.125f; s4.z *= 0.125f; s4.w *= 0.125f;
  *(float4*)(out + (size_t)t * DIM + tid * 4) = s4;
}

extern "C" void kernel_launch(void* const* d_in, const int* in_sizes, int n_in,
                              void* d_out, int out_size, void* d_ws, size_t ws_size,
                              hipStream_t stream) {
  (void)in_sizes; (void)n_in; (void)out_size;
  const float* x   = (const float*)d_in[0];
  const float* cbk = (const float*)d_in[1];
  float* out     = (float*)d_out;
  float* c2buf   = out;                   // out[0:8192], overwritten later
  float* x2buf   = out + NCB;             // out[8192:16384], overwritten later
  float* out_ids = out + (size_t)T_TOK * DIM;
  float* ws      = (float*)d_ws;

  int nsplit = 1;
  for (int s = 4; s >= 1; s >>= 1) {
    if ((size_t)s * T_TOK * 16 * 4 <= ws_size) { nsplit = s; break; }
  }
  const int ncodes = NCB / nsplit;

  sq_pairwise_kernel<<<(NCB + T_TOK) / 32, 256, 0, stream>>>(cbk, x, c2buf, x2buf);
  dist_topk_kernel<<<dim3(T_TOK / BT, nsplit), 256, 0, stream>>>(
      x, cbk, c2buf, x2buf, ws, ncodes);
  merge_gather_kernel<<<T_TOK, 192, 0, stream>>>(cbk, ws, out, out_ids, nsplit);
}